// Round 5
// baseline (109.814 us; speedup 1.0000x reference)
//
#include <hip/hip_runtime.h>

#define NUM_NODES  1048576
#define NUM_FEAT   128
#define HIDDEN     64
#define NUM_GRAPHS 4096
#define OUT_DIM    5

typedef float f32x4 __attribute__((ext_vector_type(4)));

// K1: one 128-thread block per graph (16 blocks/CU = 32 waves, single residency
// generation). Wave-cooperative 64-ary lower_bound finds the segment (wave 0
// searches g, wave 1 searches g+1, ~4 ballot rounds each, positions shared
// across blocks -> L2 broadcast). Then NT float4 streaming sum, LDS reduce,
// write the pooled mean row to ws. No weight reads here.
__global__ __launch_bounds__(128, 8) void pool_kernel(
    const float* __restrict__ x,
    const int*   __restrict__ batch,
    float* __restrict__ pooled)
{
    const int g = blockIdx.x;
    const int t = threadIdx.x;
    const int lane = t & 63;
    const int T = g + (t >> 6);   // wave 0: lower_bound(g), wave 1: lower_bound(g+1)

    // 64-ary lower_bound; invariant: answer in [lo, hi] (inclusive).
    int lo = 0, hi = NUM_NODES;
    while (hi - lo > 64) {
        const int w = hi - lo;
        const int base = lo;
        const int pos = base + (int)(((long long)w * lane) >> 6);
        const unsigned long long bal = __ballot(batch[pos] < T);
        const int m = __popcll(bal);
        if (m == 0) {
            hi = lo;                       // answer == lo
        } else {
            lo = base + (int)(((long long)w * (m - 1)) >> 6) + 1;
            if (m < 64) hi = base + (int)(((long long)w * m) >> 6);
        }
    }
    if (hi > lo) {                         // one-shot final step, width <= 64
        const int w = hi - lo;
        const bool pred = (lane < w) ? (batch[lo + lane] < T) : false;
        lo += __popcll(__ballot(pred));
    }

    __shared__ int bounds[2];
    if (lane == 0) bounds[t >> 6] = lo;
    __syncthreads();
    const int start = bounds[0];
    const int end   = bounds[1];
    const int count = end - start;

    // 128 threads: 32 column-groups (float4) x 4 row-phases.
    const int cg = t & 31;
    const int ro = t >> 5;
    int iters = count - ro + 3;
    iters = (iters > 0) ? (iters >> 2) : 0;

    const f32x4* p = reinterpret_cast<const f32x4*>(
        x + (size_t)(start + ro) * NUM_FEAT) + cg;
    const int step = NUM_FEAT;  // 128 f32x4 = 4 rows

    f32x4 acc0 = (f32x4)0.0f, acc1 = (f32x4)0.0f;
    int i = 0;
    for (; i + 2 <= iters; i += 2) {
        const f32x4 v0 = __builtin_nontemporal_load(p);
        const f32x4 v1 = __builtin_nontemporal_load(p + step);
        acc0 += v0;
        acc1 += v1;
        p += 2 * step;
    }
    if (i < iters) acc0 += __builtin_nontemporal_load(p);

    __shared__ f32x4 part[128];
    part[t] = acc0 + acc1;
    __syncthreads();

    if (t < 32) {
        f32x4 s = part[t] + part[t + 32] + part[t + 64] + part[t + 96];
        const float inv = (count > 0) ? (1.0f / (float)count) : 0.0f;
        s *= inv;
        *(reinterpret_cast<f32x4*>(pooled + (size_t)g * NUM_FEAT) + t) = s;
    }
}

// K2: MLP head. 256 blocks x 256 threads; W1/W2/W3/biases staged once per
// block into LDS (~54 KB); each block computes 16 graphs (4 at a time).
__global__ __launch_bounds__(256) void mlp_kernel(
    const float* __restrict__ pooled,
    const float* __restrict__ W1, const float* __restrict__ b1,
    const float* __restrict__ W2, const float* __restrict__ b2,
    const float* __restrict__ W3, const float* __restrict__ b3,
    float* __restrict__ out)
{
    __shared__ float W1s[NUM_FEAT * HIDDEN];   // 32 KB
    __shared__ float W2s[HIDDEN * HIDDEN];     // 16 KB
    __shared__ float W3s[HIDDEN * OUT_DIM];    // 1.25 KB
    __shared__ float b1s[HIDDEN], b2s[HIDDEN], b3s[OUT_DIM];
    __shared__ float pr[4][NUM_FEAT];
    __shared__ float h1s[4][HIDDEN], h2s[4][HIDDEN];

    const int t = threadIdx.x;

    for (int i = t; i < NUM_FEAT * HIDDEN / 4; i += 256)
        ((f32x4*)W1s)[i] = ((const f32x4*)W1)[i];
    for (int i = t; i < HIDDEN * HIDDEN / 4; i += 256)
        ((f32x4*)W2s)[i] = ((const f32x4*)W2)[i];
    for (int i = t; i < HIDDEN * OUT_DIM; i += 256)   // 320 elems > 256 threads!
        W3s[i] = W3[i];
    if (t < HIDDEN) { b1s[t] = b1[t]; b2s[t] = b2[t]; }
    if (t < OUT_DIM) b3s[t] = b3[t];
    __syncthreads();

    const int gbase = blockIdx.x * 16;
    for (int it = 0; it < 4; ++it) {
        const int g0 = gbase + it * 4;

        if (t < 128) {   // stage 4 pooled rows (coalesced f32x4)
            const int row = t >> 5, e = t & 31;
            ((f32x4*)pr[row])[e] =
                *(reinterpret_cast<const f32x4*>(pooled + (size_t)(g0 + row) * NUM_FEAT) + e);
        }
        __syncthreads();

        const int q = t >> 6, h = t & 63;
        float s = b1s[h];
        #pragma unroll 8
        for (int k = 0; k < NUM_FEAT; ++k) s = fmaf(pr[q][k], W1s[k * HIDDEN + h], s);
        h1s[q][h] = fmaxf(s, 0.0f);
        __syncthreads();

        s = b2s[h];
        #pragma unroll 8
        for (int k = 0; k < HIDDEN; ++k) s = fmaf(h1s[q][k], W2s[k * HIDDEN + h], s);
        h2s[q][h] = fmaxf(s, 0.0f);
        __syncthreads();

        if (t < 4 * OUT_DIM) {
            const int qq = t / OUT_DIM, o = t % OUT_DIM;
            float so = b3s[o];
            #pragma unroll 8
            for (int k = 0; k < HIDDEN; ++k) so = fmaf(h2s[qq][k], W3s[k * OUT_DIM + o], so);
            out[(size_t)(g0 + qq) * OUT_DIM + o] = so;
        }
        __syncthreads();
    }
}

extern "C" void kernel_launch(void* const* d_in, const int* in_sizes, int n_in,
                              void* d_out, int out_size, void* d_ws, size_t ws_size,
                              hipStream_t stream) {
    const float* x     = (const float*)d_in[0];
    const int*   batch = (const int*)d_in[1];
    const float* W1    = (const float*)d_in[2];
    const float* b1    = (const float*)d_in[3];
    const float* W2    = (const float*)d_in[4];
    const float* b2    = (const float*)d_in[5];
    const float* W3    = (const float*)d_in[6];
    const float* b3    = (const float*)d_in[7];
    float* out = (float*)d_out;

    float* pooled = (float*)d_ws;   // NUM_GRAPHS * NUM_FEAT floats (2 MB)

    pool_kernel<<<NUM_GRAPHS, 128, 0, stream>>>(x, batch, pooled);
    mlp_kernel<<<NUM_GRAPHS / 16, 256, 0, stream>>>(pooled, W1, b1, W2, b2, W3, b3, out);
}

// Round 6
// 106.077 us; speedup vs baseline: 1.0352x; 1.0352x over previous
//
#include <hip/hip_runtime.h>

#define NUM_NODES  1048576
#define NUM_FEAT   128
#define HIDDEN     64
#define NUM_GRAPHS 4096
#define OUT_DIM    5

typedef float f32x4 __attribute__((ext_vector_type(4)));

// Kernel A: streaming boundary scan. seg[g] = lower_bound(batch, g).
// Each thread i reads batch[i], batch[i-1] (coalesced); at a transition
// prev < g <= batch[i], thread i owns seg[g] = i.
__global__ __launch_bounds__(256) void seg_scan_kernel(
    const int* __restrict__ batch, int* __restrict__ seg)
{
    const int i = blockIdx.x * blockDim.x + threadIdx.x;
    if (i >= NUM_NODES) return;
    const int b = batch[i];
    const int prev = (i == 0) ? -1 : batch[i - 1];
    for (int g = prev + 1; g <= b; ++g) seg[g] = i;
    if (i == NUM_NODES - 1) {
        for (int g = b + 1; g <= NUM_GRAPHS; ++g) seg[g] = NUM_NODES;
    }
}

// Kernel B: one 128-thread block per graph (16 blocks/CU = 32 waves/CU, single
// residency generation). Plain cached float4 loads, 4 independent
// accumulators (4 loads in flight per wave), LDS reduce, fused MLP head.
__global__ __launch_bounds__(128, 8) void gcn_fused_kernel(
    const float* __restrict__ x,
    const int*   __restrict__ seg,
    const float* __restrict__ W1, const float* __restrict__ b1,
    const float* __restrict__ W2, const float* __restrict__ b2,
    const float* __restrict__ W3, const float* __restrict__ b3,
    float* __restrict__ out)
{
    const int g = blockIdx.x;
    const int t = threadIdx.x;

    const int start = seg[g];
    const int end   = seg[g + 1];
    const int count = end - start;

    // 128 threads: 32 column-groups (float4) x 4 row-phases.
    const int cg = t & 31;   // floats [4*cg, 4*cg+3]
    const int ro = t >> 5;   // row offset 0..3

    int iters = count - ro + 3;
    iters = (iters > 0) ? (iters >> 2) : 0;

    const f32x4* p = reinterpret_cast<const f32x4*>(
        x + (size_t)(start + ro) * NUM_FEAT) + cg;
    const int step = NUM_FEAT;  // 128 f32x4 = 4 rows

    f32x4 acc0 = (f32x4)0.0f, acc1 = (f32x4)0.0f;
    f32x4 acc2 = (f32x4)0.0f, acc3 = (f32x4)0.0f;
    int i = 0;
    for (; i + 4 <= iters; i += 4) {
        const f32x4 v0 = p[0 * step];
        const f32x4 v1 = p[1 * step];
        const f32x4 v2 = p[2 * step];
        const f32x4 v3 = p[3 * step];
        acc0 += v0; acc1 += v1; acc2 += v2; acc3 += v3;
        p += 4 * step;
    }
    for (; i < iters; ++i) {
        acc0 += p[0];
        p += step;
    }
    const f32x4 acc = (acc0 + acc1) + (acc2 + acc3);

    __shared__ f32x4 part[128];
    __shared__ float pooled[NUM_FEAT];
    __shared__ float h1[HIDDEN];
    __shared__ float h2[HIDDEN];

    part[t] = acc;
    __syncthreads();

    if (t < 32) {
        f32x4 s = part[t] + part[t + 32] + part[t + 64] + part[t + 96];
        const float inv = (count > 0) ? (1.0f / (float)count) : 0.0f;
        pooled[t * 4 + 0] = s.x * inv;
        pooled[t * 4 + 1] = s.y * inv;
        pooled[t * 4 + 2] = s.z * inv;
        pooled[t * 4 + 3] = s.w * inv;
    }
    __syncthreads();

    // h1 = relu(pooled @ W1 + b1); W1 [128][64] row-major -> coalesced over t
    if (t < HIDDEN) {
        float s = b1[t];
        #pragma unroll 8
        for (int k = 0; k < NUM_FEAT; ++k) s = fmaf(pooled[k], W1[k * HIDDEN + t], s);
        h1[t] = fmaxf(s, 0.0f);
    }
    __syncthreads();

    // h2 = relu(h1 @ W2 + b2); W2 [64][64]
    if (t < HIDDEN) {
        float s = b2[t];
        #pragma unroll 8
        for (int k = 0; k < HIDDEN; ++k) s = fmaf(h1[k], W2[k * HIDDEN + t], s);
        h2[t] = fmaxf(s, 0.0f);
    }
    __syncthreads();

    // out = h2 @ W3 + b3; W3 [64][5]
    if (t < OUT_DIM) {
        float s = b3[t];
        #pragma unroll 8
        for (int k = 0; k < HIDDEN; ++k) s = fmaf(h2[k], W3[k * OUT_DIM + t], s);
        out[g * OUT_DIM + t] = s;
    }
}

extern "C" void kernel_launch(void* const* d_in, const int* in_sizes, int n_in,
                              void* d_out, int out_size, void* d_ws, size_t ws_size,
                              hipStream_t stream) {
    const float* x     = (const float*)d_in[0];
    const int*   batch = (const int*)d_in[1];
    const float* W1    = (const float*)d_in[2];
    const float* b1    = (const float*)d_in[3];
    const float* W2    = (const float*)d_in[4];
    const float* b2    = (const float*)d_in[5];
    const float* W3    = (const float*)d_in[6];
    const float* b3    = (const float*)d_in[7];
    float* out = (float*)d_out;

    int* seg = (int*)d_ws;  // NUM_GRAPHS + 1 ints

    seg_scan_kernel<<<NUM_NODES / 256, 256, 0, stream>>>(batch, seg);
    gcn_fused_kernel<<<NUM_GRAPHS, 128, 0, stream>>>(x, seg, W1, b1, W2, b2, W3, b3, out);
}

// Round 7
// 105.869 us; speedup vs baseline: 1.0373x; 1.0020x over previous
//
#include <hip/hip_runtime.h>

#define NUM_NODES  1048576
#define NUM_FEAT   128
#define HIDDEN     64
#define NUM_GRAPHS 4096
#define OUT_DIM    5

typedef float f32x4 __attribute__((ext_vector_type(4)));

// K0: streaming boundary scan. seg[g] = lower_bound(batch, g).
__global__ __launch_bounds__(256) void seg_scan_kernel(
    const int* __restrict__ batch, int* __restrict__ seg)
{
    const int i = blockIdx.x * blockDim.x + threadIdx.x;
    if (i >= NUM_NODES) return;
    const int b = batch[i];
    const int prev = (i == 0) ? -1 : batch[i - 1];
    for (int g = prev + 1; g <= b; ++g) seg[g] = i;
    if (i == NUM_NODES - 1) {
        for (int g = b + 1; g <= NUM_GRAPHS; ++g) seg[g] = NUM_NODES;
    }
}

// K1: one 128-thread block per graph (16 blocks/CU = 32 waves/CU, single
// residency generation). NT float4 streaming (bypass L2/L3 allocation for the
// 512MB once-read stream), dual accumulators, LDS reduce, write pooled mean.
// No weight reads here.
__global__ __launch_bounds__(128, 8) void pool_kernel(
    const float* __restrict__ x,
    const int*   __restrict__ seg,
    float* __restrict__ pooled)
{
    const int g = blockIdx.x;
    const int t = threadIdx.x;

    const int start = seg[g];
    const int end   = seg[g + 1];
    const int count = end - start;

    const int cg = t & 31;   // floats [4*cg, 4*cg+3]
    const int ro = t >> 5;   // row offset 0..3

    int iters = count - ro + 3;
    iters = (iters > 0) ? (iters >> 2) : 0;

    const f32x4* p = reinterpret_cast<const f32x4*>(
        x + (size_t)(start + ro) * NUM_FEAT) + cg;
    const int step = NUM_FEAT;  // 128 f32x4 = 4 rows

    f32x4 acc0 = (f32x4)0.0f, acc1 = (f32x4)0.0f;
    int i = 0;
    for (; i + 2 <= iters; i += 2) {
        const f32x4 v0 = __builtin_nontemporal_load(p);
        const f32x4 v1 = __builtin_nontemporal_load(p + step);
        acc0 += v0;
        acc1 += v1;
        p += 2 * step;
    }
    if (i < iters) acc0 += __builtin_nontemporal_load(p);

    __shared__ f32x4 part[128];
    part[t] = acc0 + acc1;
    __syncthreads();

    if (t < 32) {
        f32x4 s = part[t] + part[t + 32] + part[t + 64] + part[t + 96];
        const float inv = (count > 0) ? (1.0f / (float)count) : 0.0f;
        s *= inv;
        *(reinterpret_cast<f32x4*>(pooled + (size_t)g * NUM_FEAT) + t) = s;
    }
}

// K2: MLP head. 512 blocks x 256 threads (2 blocks/CU, 8 waves/CU); W1/W2/W3
// staged once per block into LDS (~54 KB); each block computes 8 graphs.
// W L2-traffic: 512 x 48KB = 24 MB (vs 190 MB if done per-graph-block).
__global__ __launch_bounds__(256) void mlp_kernel(
    const float* __restrict__ pooled,
    const float* __restrict__ W1, const float* __restrict__ b1,
    const float* __restrict__ W2, const float* __restrict__ b2,
    const float* __restrict__ W3, const float* __restrict__ b3,
    float* __restrict__ out)
{
    __shared__ float W1s[NUM_FEAT * HIDDEN];   // 32 KB
    __shared__ float W2s[HIDDEN * HIDDEN];     // 16 KB
    __shared__ float W3s[HIDDEN * OUT_DIM];    // 1.25 KB
    __shared__ float b1s[HIDDEN], b2s[HIDDEN], b3s[OUT_DIM];
    __shared__ float pr[4][NUM_FEAT];
    __shared__ float h1s[4][HIDDEN], h2s[4][HIDDEN];

    const int t = threadIdx.x;

    for (int i = t; i < NUM_FEAT * HIDDEN / 4; i += 256)
        ((f32x4*)W1s)[i] = ((const f32x4*)W1)[i];
    for (int i = t; i < HIDDEN * HIDDEN / 4; i += 256)
        ((f32x4*)W2s)[i] = ((const f32x4*)W2)[i];
    for (int i = t; i < HIDDEN * OUT_DIM; i += 256)   // 320 elems
        W3s[i] = W3[i];
    if (t < HIDDEN) { b1s[t] = b1[t]; b2s[t] = b2[t]; }
    if (t < OUT_DIM) b3s[t] = b3[t];
    __syncthreads();

    const int gbase = blockIdx.x * 8;
    for (int it = 0; it < 2; ++it) {
        const int g0 = gbase + it * 4;

        if (t < 128) {   // stage 4 pooled rows (coalesced f32x4)
            const int row = t >> 5, e = t & 31;
            ((f32x4*)pr[row])[e] =
                *(reinterpret_cast<const f32x4*>(pooled + (size_t)(g0 + row) * NUM_FEAT) + e);
        }
        __syncthreads();

        const int q = t >> 6, h = t & 63;
        float s = b1s[h];
        #pragma unroll 8
        for (int k = 0; k < NUM_FEAT; ++k) s = fmaf(pr[q][k], W1s[k * HIDDEN + h], s);
        h1s[q][h] = fmaxf(s, 0.0f);
        __syncthreads();

        s = b2s[h];
        #pragma unroll 8
        for (int k = 0; k < HIDDEN; ++k) s = fmaf(h1s[q][k], W2s[k * HIDDEN + h], s);
        h2s[q][h] = fmaxf(s, 0.0f);
        __syncthreads();

        if (t < 4 * OUT_DIM) {
            const int qq = t / OUT_DIM, o = t % OUT_DIM;
            float so = b3s[o];
            #pragma unroll 8
            for (int k = 0; k < HIDDEN; ++k) so = fmaf(h2s[qq][k], W3s[k * OUT_DIM + o], so);
            out[(size_t)(g0 + qq) * OUT_DIM + o] = so;
        }
        __syncthreads();
    }
}

extern "C" void kernel_launch(void* const* d_in, const int* in_sizes, int n_in,
                              void* d_out, int out_size, void* d_ws, size_t ws_size,
                              hipStream_t stream) {
    const float* x     = (const float*)d_in[0];
    const int*   batch = (const int*)d_in[1];
    const float* W1    = (const float*)d_in[2];
    const float* b1    = (const float*)d_in[3];
    const float* W2    = (const float*)d_in[4];
    const float* b2    = (const float*)d_in[5];
    const float* W3    = (const float*)d_in[6];
    const float* b3    = (const float*)d_in[7];
    float* out = (float*)d_out;

    int*   seg    = (int*)d_ws;                          // 4097 ints
    float* pooled = (float*)((char*)d_ws + 32768);       // 4096*128 floats (2MB)

    seg_scan_kernel<<<NUM_NODES / 256, 256, 0, stream>>>(batch, seg);
    pool_kernel<<<NUM_GRAPHS, 128, 0, stream>>>(x, seg, pooled);
    mlp_kernel<<<NUM_GRAPHS / 8, 256, 0, stream>>>(pooled, W1, b1, W2, b2, W3, b3, out);
}

// Round 8
// 93.082 us; speedup vs baseline: 1.1798x; 1.1374x over previous
//
#include <hip/hip_runtime.h>

#define NUM_NODES  1048576
#define NUM_FEAT   128
#define HIDDEN     64
#define NUM_GRAPHS 4096
#define OUT_DIM    5

typedef float f32x4 __attribute__((ext_vector_type(4)));

// K0: streaming boundary scan. seg[g] = lower_bound(batch, g).
__global__ __launch_bounds__(256) void seg_scan_kernel(
    const int* __restrict__ batch, int* __restrict__ seg)
{
    const int i = blockIdx.x * blockDim.x + threadIdx.x;
    if (i >= NUM_NODES) return;
    const int b = batch[i];
    const int prev = (i == 0) ? -1 : batch[i - 1];
    for (int g = prev + 1; g <= b; ++g) seg[g] = i;
    if (i == NUM_NODES - 1) {
        for (int g = b + 1; g <= NUM_GRAPHS; ++g) seg[g] = NUM_NODES;
    }
}

// K1: one 128-thread block per graph (16 blocks/CU = 32 waves/CU, single
// residency generation). NT float4 streaming with 6 loads in flight per wave
// (tail waves run latency-bound at ~3x the 2-deep solo rate), LDS reduce,
// fused MLP head (overlapped epilogue - R7 proved splitting it costs more).
__global__ __launch_bounds__(128, 8) void gcn_fused_kernel(
    const float* __restrict__ x,
    const int*   __restrict__ seg,
    const float* __restrict__ W1, const float* __restrict__ b1,
    const float* __restrict__ W2, const float* __restrict__ b2,
    const float* __restrict__ W3, const float* __restrict__ b3,
    float* __restrict__ out)
{
    const int g = blockIdx.x;
    const int t = threadIdx.x;

    const int start = seg[g];
    const int end   = seg[g + 1];
    const int count = end - start;

    // 128 threads: 32 column-groups (float4) x 4 row-phases.
    const int cg = t & 31;   // floats [4*cg, 4*cg+3]
    const int ro = t >> 5;   // row offset 0..3

    int iters = count - ro + 3;
    iters = (iters > 0) ? (iters >> 2) : 0;

    const f32x4* p = reinterpret_cast<const f32x4*>(
        x + (size_t)(start + ro) * NUM_FEAT) + cg;
    const int step = NUM_FEAT;  // 128 f32x4 = 4 rows

    f32x4 acc0 = (f32x4)0.0f, acc1 = (f32x4)0.0f, acc2 = (f32x4)0.0f;
    int i = 0;
    // main loop: 6 independent NT loads in flight per iteration
    for (; i + 6 <= iters; i += 6) {
        const f32x4 v0 = __builtin_nontemporal_load(p + 0 * step);
        const f32x4 v1 = __builtin_nontemporal_load(p + 1 * step);
        const f32x4 v2 = __builtin_nontemporal_load(p + 2 * step);
        const f32x4 v3 = __builtin_nontemporal_load(p + 3 * step);
        const f32x4 v4 = __builtin_nontemporal_load(p + 4 * step);
        const f32x4 v5 = __builtin_nontemporal_load(p + 5 * step);
        acc0 += v0; acc1 += v1; acc2 += v2;
        acc0 += v3; acc1 += v4; acc2 += v5;
        p += 6 * step;
    }
    // remainder (<=5): issue all predicated loads in one batch, not serially
    {
        const int rem = iters - i;
        const f32x4 r0 = (0 < rem) ? __builtin_nontemporal_load(p + 0 * step) : (f32x4)0.0f;
        const f32x4 r1 = (1 < rem) ? __builtin_nontemporal_load(p + 1 * step) : (f32x4)0.0f;
        const f32x4 r2 = (2 < rem) ? __builtin_nontemporal_load(p + 2 * step) : (f32x4)0.0f;
        const f32x4 r3 = (3 < rem) ? __builtin_nontemporal_load(p + 3 * step) : (f32x4)0.0f;
        const f32x4 r4 = (4 < rem) ? __builtin_nontemporal_load(p + 4 * step) : (f32x4)0.0f;
        acc0 += r0 + r3;
        acc1 += r1 + r4;
        acc2 += r2;
    }
    const f32x4 acc = acc0 + acc1 + acc2;

    __shared__ f32x4 part[128];
    __shared__ float pooled[NUM_FEAT];
    __shared__ float h1[HIDDEN];
    __shared__ float h2[HIDDEN];

    part[t] = acc;
    __syncthreads();

    if (t < 32) {
        f32x4 s = part[t] + part[t + 32] + part[t + 64] + part[t + 96];
        const float inv = (count > 0) ? (1.0f / (float)count) : 0.0f;
        pooled[t * 4 + 0] = s.x * inv;
        pooled[t * 4 + 1] = s.y * inv;
        pooled[t * 4 + 2] = s.z * inv;
        pooled[t * 4 + 3] = s.w * inv;
    }
    __syncthreads();

    // h1 = relu(pooled @ W1 + b1); W1 [128][64] row-major -> coalesced over t
    if (t < HIDDEN) {
        float s = b1[t];
        #pragma unroll 8
        for (int k = 0; k < NUM_FEAT; ++k) s = fmaf(pooled[k], W1[k * HIDDEN + t], s);
        h1[t] = fmaxf(s, 0.0f);
    }
    __syncthreads();

    // h2 = relu(h1 @ W2 + b2); W2 [64][64]
    if (t < HIDDEN) {
        float s = b2[t];
        #pragma unroll 8
        for (int k = 0; k < HIDDEN; ++k) s = fmaf(h1[k], W2[k * HIDDEN + t], s);
        h2[t] = fmaxf(s, 0.0f);
    }
    __syncthreads();

    // out = h2 @ W3 + b3; W3 [64][5]
    if (t < OUT_DIM) {
        float s = b3[t];
        #pragma unroll 8
        for (int k = 0; k < HIDDEN; ++k) s = fmaf(h2[k], W3[k * OUT_DIM + t], s);
        out[g * OUT_DIM + t] = s;
    }
}

extern "C" void kernel_launch(void* const* d_in, const int* in_sizes, int n_in,
                              void* d_out, int out_size, void* d_ws, size_t ws_size,
                              hipStream_t stream) {
    const float* x     = (const float*)d_in[0];
    const int*   batch = (const int*)d_in[1];
    const float* W1    = (const float*)d_in[2];
    const float* b1    = (const float*)d_in[3];
    const float* W2    = (const float*)d_in[4];
    const float* b2    = (const float*)d_in[5];
    const float* W3    = (const float*)d_in[6];
    const float* b3    = (const float*)d_in[7];
    float* out = (float*)d_out;

    int* seg = (int*)d_ws;  // NUM_GRAPHS + 1 ints

    seg_scan_kernel<<<NUM_NODES / 256, 256, 0, stream>>>(batch, seg);
    gcn_fused_kernel<<<NUM_GRAPHS, 128, 0, stream>>>(x, seg, W1, b1, W2, b2, W3, b3, out);
}

// Round 9
// 92.564 us; speedup vs baseline: 1.1864x; 1.0056x over previous
//
#include <hip/hip_runtime.h>

#define NUM_NODES  1048576
#define NUM_FEAT   128
#define HIDDEN     64
#define NUM_GRAPHS 4096
#define OUT_DIM    5

typedef float f32x4 __attribute__((ext_vector_type(4)));

// K0: streaming boundary scan. seg[g] = lower_bound(batch, g).
__global__ __launch_bounds__(256) void seg_scan_kernel(
    const int* __restrict__ batch, int* __restrict__ seg)
{
    const int i = blockIdx.x * blockDim.x + threadIdx.x;
    if (i >= NUM_NODES) return;
    const int b = batch[i];
    const int prev = (i == 0) ? -1 : batch[i - 1];
    for (int g = prev + 1; g <= b; ++g) seg[g] = i;
    if (i == NUM_NODES - 1) {
        for (int g = b + 1; g <= NUM_GRAPHS; ++g) seg[g] = NUM_NODES;
    }
}

// K1: one 256-thread block per graph (8 resident blocks/CU = 32 waves, second
// half of the grid refills slots as blocks finish -> packed tail; 4 waves per
// block halve the per-thread drain length). NT float4 streaming, 6 loads in
// flight, predicated remainder, LDS reduce, fused MLP head.
__global__ __launch_bounds__(256, 8) void gcn_fused_kernel(
    const float* __restrict__ x,
    const int*   __restrict__ seg,
    const float* __restrict__ W1, const float* __restrict__ b1,
    const float* __restrict__ W2, const float* __restrict__ b2,
    const float* __restrict__ W3, const float* __restrict__ b3,
    float* __restrict__ out)
{
    const int g = blockIdx.x;
    const int t = threadIdx.x;

    const int start = seg[g];
    const int end   = seg[g + 1];
    const int count = end - start;

    // 256 threads: 32 column-groups (float4) x 8 row-phases.
    const int cg = t & 31;   // floats [4*cg, 4*cg+3]
    const int ro = t >> 5;   // row offset 0..7

    int iters = count - ro + 7;
    iters = (iters > 0) ? (iters >> 3) : 0;

    const f32x4* p = reinterpret_cast<const f32x4*>(
        x + (size_t)(start + ro) * NUM_FEAT) + cg;
    const int step = 2 * NUM_FEAT;  // 8 rows = 256 f32x4 per phase stride

    f32x4 acc0 = (f32x4)0.0f, acc1 = (f32x4)0.0f, acc2 = (f32x4)0.0f;
    int i = 0;
    for (; i + 6 <= iters; i += 6) {
        const f32x4 v0 = __builtin_nontemporal_load(p + 0 * step);
        const f32x4 v1 = __builtin_nontemporal_load(p + 1 * step);
        const f32x4 v2 = __builtin_nontemporal_load(p + 2 * step);
        const f32x4 v3 = __builtin_nontemporal_load(p + 3 * step);
        const f32x4 v4 = __builtin_nontemporal_load(p + 4 * step);
        const f32x4 v5 = __builtin_nontemporal_load(p + 5 * step);
        acc0 += v0; acc1 += v1; acc2 += v2;
        acc0 += v3; acc1 += v4; acc2 += v5;
        p += 6 * step;
    }
    {
        const int rem = iters - i;
        const f32x4 r0 = (0 < rem) ? __builtin_nontemporal_load(p + 0 * step) : (f32x4)0.0f;
        const f32x4 r1 = (1 < rem) ? __builtin_nontemporal_load(p + 1 * step) : (f32x4)0.0f;
        const f32x4 r2 = (2 < rem) ? __builtin_nontemporal_load(p + 2 * step) : (f32x4)0.0f;
        const f32x4 r3 = (3 < rem) ? __builtin_nontemporal_load(p + 3 * step) : (f32x4)0.0f;
        const f32x4 r4 = (4 < rem) ? __builtin_nontemporal_load(p + 4 * step) : (f32x4)0.0f;
        acc0 += r0 + r3;
        acc1 += r1 + r4;
        acc2 += r2;
    }
    const f32x4 acc = acc0 + acc1 + acc2;

    __shared__ f32x4 part[256];
    __shared__ float pooled[NUM_FEAT];
    __shared__ float h1[HIDDEN];
    __shared__ float h2[HIDDEN];

    part[t] = acc;
    __syncthreads();

    if (t < 32) {
        f32x4 s = ((part[t] + part[t + 32]) + (part[t + 64] + part[t + 96]))
                + ((part[t + 128] + part[t + 160]) + (part[t + 192] + part[t + 224]));
        const float inv = (count > 0) ? (1.0f / (float)count) : 0.0f;
        pooled[t * 4 + 0] = s.x * inv;
        pooled[t * 4 + 1] = s.y * inv;
        pooled[t * 4 + 2] = s.z * inv;
        pooled[t * 4 + 3] = s.w * inv;
    }
    __syncthreads();

    // h1 = relu(pooled @ W1 + b1); W1 [128][64] row-major -> coalesced over t
    if (t < HIDDEN) {
        float s = b1[t];
        #pragma unroll 8
        for (int k = 0; k < NUM_FEAT; ++k) s = fmaf(pooled[k], W1[k * HIDDEN + t], s);
        h1[t] = fmaxf(s, 0.0f);
    }
    __syncthreads();

    // h2 = relu(h1 @ W2 + b2); W2 [64][64]
    if (t < HIDDEN) {
        float s = b2[t];
        #pragma unroll 8
        for (int k = 0; k < HIDDEN; ++k) s = fmaf(h1[k], W2[k * HIDDEN + t], s);
        h2[t] = fmaxf(s, 0.0f);
    }
    __syncthreads();

    // out = h2 @ W3 + b3; W3 [64][5]
    if (t < OUT_DIM) {
        float s = b3[t];
        #pragma unroll 8
        for (int k = 0; k < HIDDEN; ++k) s = fmaf(h2[k], W3[k * OUT_DIM + t], s);
        out[g * OUT_DIM + t] = s;
    }
}

extern "C" void kernel_launch(void* const* d_in, const int* in_sizes, int n_in,
                              void* d_out, int out_size, void* d_ws, size_t ws_size,
                              hipStream_t stream) {
    const float* x     = (const float*)d_in[0];
    const int*   batch = (const int*)d_in[1];
    const float* W1    = (const float*)d_in[2];
    const float* b1    = (const float*)d_in[3];
    const float* W2    = (const float*)d_in[4];
    const float* b2    = (const float*)d_in[5];
    const float* W3    = (const float*)d_in[6];
    const float* b3    = (const float*)d_in[7];
    float* out = (float*)d_out;

    int* seg = (int*)d_ws;  // NUM_GRAPHS + 1 ints

    seg_scan_kernel<<<NUM_NODES / 256, 256, 0, stream>>>(batch, seg);
    gcn_fused_kernel<<<NUM_GRAPHS, 256, 0, stream>>>(x, seg, W1, b1, W2, b2, W3, b3, out);
}